// Round 5
// baseline (863.936 us; speedup 1.0000x reference)
//
#include <hip/hip_runtime.h>
#include <cstdint>
#include <cstddef>

#define T_STEPS 64
#define F_INP 5
#define LOG2E 1.44269504088896340736f

typedef _Float16 f16x8 __attribute__((ext_vector_type(8)));
typedef float f32x4 __attribute__((ext_vector_type(4)));
typedef float f32x2 __attribute__((ext_vector_type(2)));
typedef unsigned int u32x2 __attribute__((ext_vector_type(2)));

__device__ __forceinline__ float leaky(float x, float s){ return x>0.f? x : s*x; }
__device__ __forceinline__ float rcpf(float x){ return __builtin_amdgcn_rcpf(x); }

// packed deg-4 exp2: z MUST be pre-clamped to [-44,44].
// magic-add round-to-nearest; 2^f Taylor deg-4 (rel err ~3e-5 at |f|=0.5,
// far below the f16 h-storage noise); exponent scale via integer bits.
// Lowers to v_pk_add/v_pk_fma/v_pk_mul + 2 scalar lshl_add per pair.
__device__ __forceinline__ f32x2 exp2_pk(f32x2 z){
  const f32x2 MAGIC = {12582912.f, 12582912.f};       // 1.5 * 2^23
  f32x2 t = z + MAGIC;
  f32x2 n = t - MAGIC;
  f32x2 f = z - n;
  const f32x2 C4 = {0.0096181291f, 0.0096181291f};
  const f32x2 C3 = {0.0555041087f, 0.0555041087f};
  const f32x2 C2 = {0.2402265069f, 0.2402265069f};
  const f32x2 C1 = {0.6931471806f, 0.6931471806f};
  const f32x2 C0 = {1.f, 1.f};
  f32x2 p = C4;
  p = __builtin_elementwise_fma(p, f, C3);
  p = __builtin_elementwise_fma(p, f, C2);
  p = __builtin_elementwise_fma(p, f, C1);
  p = __builtin_elementwise_fma(p, f, C0);
  u32x2 ti = __builtin_bit_cast(u32x2, t);
  u32x2 sb;
  sb.x = (ti.x << 23) + 0x3F800000u;
  sb.y = (ti.y << 23) + 0x3F800000u;
  return p * __builtin_bit_cast(f32x2, sb);
}

__device__ __forceinline__ f32x2 cl44(f32x2 v){
  const f32x2 lo = {-44.f,-44.f}, hi = {44.f,44.f};
  return __builtin_elementwise_min(__builtin_elementwise_max(v, lo), hi);
}

#define MF(a,b,c) __builtin_amdgcn_mfma_f32_16x16x32_f16((a),(b),(c),0,0,0)

// ---------------- MFMA LSTM + fused GAT-prep epilogue.
// 32 nodes/block, 4 waves lockstep. Wave wq owns gate-cols [16wq,16wq+16).
// Round-5: activation rewritten on the packed-f32 pipe:
//  - exp2 via deg-4 poly on v_pk_fma_f32 (~10-12cy/elem vs 16cy trans-block)
//  - reciprocals paired across elements: rcp(Q0*Q1) + 2 muls replaces 2 rcps
//  - all activation algebra on f32x2 element-pairs
// Gate args clamped +-44 (sigmoid/tanh saturated; data range |z|<~30).
// NOTE: __launch_bounds__ 2nd arg MUST stay 4. (256,5) -> 96-reg budget ->
// spills (FETCH 64->160MB, r4); (256,8) -> 32-reg catastrophe (r1). The live
// set needs ~128 unified regs; occupancy is structurally 4 waves/SIMD.
__global__ __launch_bounds__(256, 4) void lstm_mfma(
    const float* __restrict__ x, const float* __restrict__ W_ih,
    const float* __restrict__ W_hh, const float* __restrict__ b_ih,
    const float* __restrict__ b_hh, const float* __restrict__ vcomb,
    float2* __restrict__ asx, float* __restrict__ a_dst,
    float* __restrict__ denom, float* __restrict__ oacc, int N)
{
  __shared__ __align__(16) _Float16 Hs0[32][64];
  __shared__ __align__(16) _Float16 Hs1[32][64];
  __shared__ __align__(16) _Float16 Xs0[32][8];
  __shared__ __align__(16) _Float16 Xs1[32][8];
  __shared__ __align__(16) _Float16 Zero8[8];
  __shared__ __align__(16) float    Hf[32][65];   // f32 final h (pad 65)

  const int tid   = threadIdx.x;
  const int lane  = tid & 63;
  const int wq    = tid >> 6;      // 0..3 gate-col slice
  const int col16 = lane & 15;
  const int grp   = lane >> 4;
  const int base  = blockIdx.x * 32;

  // ---- B fragments (fp16). g gate (n==2) scaled 2*LOG2E; i,f,o by LOG2E.
  f16x8 Bh[4][2], Bx[4];
  #pragma unroll
  for (int n=0;n<4;n++){
    const float sc = (n==2) ? 2.f*LOG2E : LOG2E;
    const int gate = n*64 + wq*16 + col16;
    #pragma unroll
    for (int kk=0;kk<2;kk++){
      const float* p = W_hh + gate*64 + kk*32 + grp*8;
      #pragma unroll
      for (int e=0;e<8;e++) Bh[n][kk][e] = (_Float16)(p[e]*sc);
    }
    f16x8 bx = {0,0,0,0,0,0,0,0};
    if (grp==0){
      #pragma unroll
      for (int e=0;e<5;e++) bx[e] = (_Float16)(W_ih[gate*5+e]*sc);
      bx[5] = (_Float16)((b_ih[gate]+b_hh[gate])*sc);
    }
    Bx[n] = bx;
  }

  // zero Hs0 (4 KB = 256 float4) + Zero8
  ((float4*)&Hs0[0][0])[tid] = float4{0.f,0.f,0.f,0.f};
  if (tid==0) ((float4*)Zero8)[0] = float4{0.f,0.f,0.f,0.f};

  // ---- distributed x staging: thread tid<160 owns (node=tid/5, elem=tid%5)
  const int  xn5  = tid/5, xe5 = tid - xn5*5;
  const bool xact = (tid < 160);
  const int  gxnode = base + xn5;
  const bool xlive  = xact && (gxnode < N);
  const float* xptr = x + (size_t)(xlive ? gxnode : 0)*(T_STEPS*F_INP) + xe5 + F_INP;
  if (xact){
    float v0 = xlive ? x[(size_t)gxnode*(T_STEPS*F_INP) + xe5] : 0.f;
    Xs0[xn5][xe5] = (_Float16)v0;
  }
  if (tid < 32){
    Xs0[tid][5]=(_Float16)1.f; Xs0[tid][6]=(_Float16)0.f; Xs0[tid][7]=(_Float16)0.f;
    Xs1[tid][5]=(_Float16)1.f; Xs1[tid][6]=(_Float16)0.f; Xs1[tid][7]=(_Float16)0.f;
  }

  // loop-invariant LDS element offsets
  const int sw = (col16&7)<<3;
  int roff0[2], roff1[2], xoffm[2], soff[2][4];
  const int j = wq*16 + col16;
  #pragma unroll
  for (int m=0;m<2;m++){
    const int nodeA = 16*m + col16;
    roff0[m] = nodeA*64 + ((grp*8) ^ sw);
    roff1[m] = nodeA*64 + ((32 + grp*8) ^ sw);
    xoffm[m] = nodeA*8;
    #pragma unroll
    for (int r=0;r<4;r++){
      const int node = 16*m + 4*grp + r;
      soff[m][r] = node*64 + (j ^ ((4*(grp&1)+r)<<3));
    }
  }

  float creg[2][4];
  #pragma unroll
  for (int m=0;m<2;m++)
    #pragma unroll
    for (int r=0;r<4;r++) creg[m][r]=0.f;

  __syncthreads();

#define LSTM_STEP(HC, HN, XC, XN, XOFF, LAST) {                                \
    float xval = 0.f;                                                          \
    if (!(LAST) && xlive) xval = xptr[XOFF];                                   \
    _Pragma("unroll")                                                          \
    for (int m=0;m<2;m++){                                                     \
      f16x8 a0 = *(const f16x8*)(&HC[0][0] + roff0[m]);                        \
      f16x8 a1 = *(const f16x8*)(&HC[0][0] + roff1[m]);                        \
      const _Float16* px = (grp==0) ? (&XC[0][0] + xoffm[m]) : Zero8;          \
      f16x8 ax = *(const f16x8*)px;                                            \
      f32x4 z4 = f32x4{0.f,0.f,0.f,0.f};                                       \
      f32x4 c0=z4, c1=z4, c2=z4, c3=z4;                                        \
      c0 = MF(a0, Bh[0][0], c0); c1 = MF(a0, Bh[1][0], c1);                    \
      c2 = MF(a0, Bh[2][0], c2); c3 = MF(a0, Bh[3][0], c3);                    \
      c0 = MF(a1, Bh[0][1], c0); c1 = MF(a1, Bh[1][1], c1);                    \
      c2 = MF(a1, Bh[2][1], c2); c3 = MF(a1, Bh[3][1], c3);                    \
      c0 = MF(ax, Bx[0],    c0); c1 = MF(ax, Bx[1],    c1);                    \
      c2 = MF(ax, Bx[2],    c2); c3 = MF(ax, Bx[3],    c3);                    \
      _Pragma("unroll")                                                        \
      for (int pr=0; pr<2; ++pr){                                              \
        f32x2 zi = { c0[2*pr], c0[2*pr+1] };                                   \
        f32x2 zf = { c1[2*pr], c1[2*pr+1] };                                   \
        f32x2 zg = { c2[2*pr], c2[2*pr+1] };                                   \
        f32x2 zo = { c3[2*pr], c3[2*pr+1] };                                   \
        f32x2 e_i = exp2_pk(cl44(-zi));                                        \
        f32x2 e_f = exp2_pk(cl44(-zf));                                        \
        f32x2 e_g = exp2_pk(cl44(zg));                                         \
        f32x2 e_o = exp2_pk(cl44(-zo));                                        \
        const f32x2 one = {1.f,1.f};                                           \
        f32x2 Ag = (one+e_i)*(one+e_g);                                        \
        f32x2 Bf = one+e_f;                                                    \
        f32x2 Q  = Ag*Bf;                                                      \
        float rq = rcpf(Q.x*Q.y);                                              \
        f32x2 rD = { rq*Q.y, rq*Q.x };                                         \
        f32x2 cold = { creg[m][2*pr], creg[m][2*pr+1] };                       \
        f32x2 cn = (cold*Ag + (e_g-one)*Bf)*rD;                                \
        creg[m][2*pr] = cn.x; creg[m][2*pr+1] = cn.y;                          \
        f32x2 e_c = exp2_pk(cl44(cn*(2.f*LOG2E)));                             \
        f32x2 D2 = (one+e_o)*(one+e_c);                                        \
        float rd = rcpf(D2.x*D2.y);                                            \
        f32x2 rH = { rd*D2.y, rd*D2.x };                                       \
        f32x2 hv = (e_c-one)*rH;                                               \
        if (LAST){                                                             \
          Hf[16*m+4*grp+2*pr  ][j] = hv.x;                                     \
          Hf[16*m+4*grp+2*pr+1][j] = hv.y;                                     \
        } else {                                                               \
          (&HN[0][0])[soff[m][2*pr  ]] = (_Float16)hv.x;                       \
          (&HN[0][0])[soff[m][2*pr+1]] = (_Float16)hv.y;                       \
        }                                                                      \
      }                                                                        \
    }                                                                          \
    if (!(LAST) && xact) XN[xn5][xe5] = (_Float16)xval;                        \
  }

  for (int tt=0; tt<T_STEPS/2; ++tt){
    LSTM_STEP(Hs0, Hs1, Xs0, Xs1, 0, false);
    __syncthreads();
    LSTM_STEP(Hs1, Hs0, Xs1, Xs0, F_INP, (tt==T_STEPS/2-1));
    __syncthreads();
    xptr += 2*F_INP;
  }
#undef LSTM_STEP

  // ---- fused GAT prep: 8 threads per node, dot h (f32, LDS) with vcomb.
  const int en = tid >> 3, es = tid & 7;
  const int gn2 = base + en;
  float as=0.f, ad=0.f, xf=0.f;
  #pragma unroll
  for (int q=0;q<8;q++){
    float hv = Hf[en][es*8+q];
    as = fmaf(hv, vcomb[es*8+q],     as);
    ad = fmaf(hv, vcomb[64+es*8+q],  ad);
    xf = fmaf(hv, vcomb[128+es*8+q], xf);
  }
  #pragma unroll
  for (int off=1; off<8; off<<=1){
    as += __shfl_xor(as, off);
    ad += __shfl_xor(ad, off);
    xf += __shfl_xor(xf, off);
  }
  if (es==0 && gn2 < N){
    asx[gn2]   = float2{as, xf};
    a_dst[gn2] = ad;
    denom[gn2] = 0.f;
    oacc[gn2]  = 0.f;
  }
}

// ---------------- GAT setup (one 64-thread block), wave-parallel:
// mode detect via ballot; vcomb = gat_w^T {att_src, att_dst, fc_w};
// bias-dot scalar via shfl reduce.
__global__ void gat_setup(const int* __restrict__ ei,
                          const float* __restrict__ gat_w,
                          const float* __restrict__ att_src,
                          const float* __restrict__ att_dst,
                          const float* __restrict__ fc_w,
                          const float* __restrict__ gat_bias,
                          const float* __restrict__ fc_b,
                          float* __restrict__ vcomb,
                          unsigned* __restrict__ mode)
{
  int j = threadIdx.x;   // 0..63, one full wave
  unsigned long long nz = __ballot(ei[2*j+1] != 0);
  float bdp = gat_bias[j]*fc_w[j];
  #pragma unroll
  for (int off=32; off; off>>=1) bdp += __shfl_down(bdp, off);
  if (j==0){
    *mode = (nz==0ULL) ? 1u : 0u;
    vcomb[192] = bdp + fc_b[0];
  }
  float va=0.f, vd=0.f, vf=0.f;
  #pragma unroll 8
  for (int k=0;k<64;k++){
    float g = gat_w[k*64+j];
    va += att_src[k]*g;
    vd += att_dst[k]*g;
    vf += fc_w[k]*g;
  }
  vcomb[j]=va; vcomb[64+j]=vd; vcomb[128+j]=vf;
}

__device__ __forceinline__ void load_edge(const int* ei, unsigned mode,
                                          long long e, long long E,
                                          int& s, int& d)
{
  if (e>=E){ s=d=(int)(e-E); }
  else if (mode){
    const long long* e64 = (const long long*)ei;
    s=(int)e64[e]; d=(int)e64[E+e];
  } else {
    s=ei[e]; d=ei[E+e];
  }
}

// single pass: softmax normalization deferred to finalize.
// out[d] = (sum ew*xf_s)/(sum ew). asx packs {a_src, xfv} -> one 8B gather.
__global__ __launch_bounds__(256) void edge_pass(
    const int* __restrict__ ei, const unsigned* __restrict__ mode_p,
    const float2* __restrict__ asx, const float* __restrict__ a_dst,
    float* __restrict__ denom, float* __restrict__ oacc,
    long long E, long long total)
{
  long long e = (long long)blockIdx.x*256 + threadIdx.x;
  if (e>=total) return;
  int s,d;
  load_edge(ei, *mode_p, e, E, s, d);
  float2 sv = asx[s];
  float al = leaky(sv.x + a_dst[d], 0.2f);
  float ew = __expf(al);
  atomicAdd(&denom[d], ew);
  atomicAdd(&oacc[d], ew * sv.y);
}

__global__ __launch_bounds__(256) void finalize(
    const float* __restrict__ oacc, const float* __restrict__ denom,
    const float* __restrict__ vcomb, float* __restrict__ out, int N)
{
  int n = blockIdx.x*256+threadIdx.x;
  if (n>=N) return;
  float v = oacc[n] * rcpf(denom[n]) + vcomb[192];
  out[n] = leaky(v, 0.01f);
}

extern "C" void kernel_launch(void* const* d_in, const int* in_sizes, int n_in,
                              void* d_out, int out_size, void* d_ws, size_t ws_size,
                              hipStream_t stream)
{
  const float* x      = (const float*)d_in[0];
  const float* W_ih   = (const float*)d_in[1];
  const float* W_hh   = (const float*)d_in[2];
  const float* b_ih   = (const float*)d_in[3];
  const float* b_hh   = (const float*)d_in[4];
  const float* gat_w  = (const float*)d_in[5];
  const float* att_s  = (const float*)d_in[6];
  const float* att_d  = (const float*)d_in[7];
  const float* gat_b  = (const float*)d_in[8];
  const float* fc_w   = (const float*)d_in[9];
  const float* fc_b   = (const float*)d_in[10];
  const int*   ei     = (const int*)d_in[11];

  const int N = in_sizes[0]/(T_STEPS*F_INP);
  const long long E = in_sizes[11]/2;
  const long long total = E + N;

  float* ws = (float*)d_ws;
  size_t off = 0;
  float2* asx    = (float2*)(ws + off); off += (size_t)2*N;
  float* a_dst   = ws + off; off += (size_t)N;
  float* denom   = ws + off; off += (size_t)N;
  float* oacc    = ws + off; off += (size_t)N;
  float* vcomb   = ws + off; off += 256;
  unsigned* mode = (unsigned*)(ws + off); off += 1;

  gat_setup<<<1,64,0,stream>>>(ei, gat_w, att_s, att_d, fc_w, gat_b, fc_b, vcomb, mode);

  lstm_mfma<<<dim3((N+31)/32), dim3(256), 0, stream>>>(
      x, W_ih, W_hh, b_ih, b_hh, vcomb, asx, a_dst, denom, oacc, N);

  int eb = (int)((total+255)/256);
  edge_pass<<<dim3(eb), dim3(256), 0, stream>>>(ei, mode, asx, a_dst, denom, oacc, E, total);

  finalize<<<dim3((N+255)/256), dim3(256), 0, stream>>>(oacc, denom, vcomb, (float*)d_out, N);
}

// Round 8
// 648.892 us; speedup vs baseline: 1.3314x; 1.3314x over previous
//
#include <hip/hip_runtime.h>
#include <cstdint>
#include <cstddef>

#define T_STEPS 64
#define F_INP 5
#define LOG2E 1.44269504088896340736f

typedef _Float16 f16x8 __attribute__((ext_vector_type(8)));
typedef float f32x4 __attribute__((ext_vector_type(4)));

__device__ __forceinline__ float leaky(float x, float s){ return x>0.f? x : s*x; }
__device__ __forceinline__ float rcpf(float x){ return __builtin_amdgcn_rcpf(x); }
__device__ __forceinline__ float exp2fast(float x){ return __builtin_amdgcn_exp2f(x); }

#define MF(a,b,c) __builtin_amdgcn_mfma_f32_16x16x32_f16((a),(b),(c),0,0,0)

// ---------------- MFMA LSTM + fused GAT-prep epilogue.
// 32 nodes/block, 4 waves lockstep. Wave wq owns gate-cols [16wq,16wq+16).
// Activation: the r3-PROVEN form. 5 exp + 2 DIRECT rcp per cell element.
//   cn = (c*Ag + (e_g-1)*Bf) / (Ag*Bf),  Ag=(1+e_i)(1+e_g), Bf=1+e_f
//   hv = (e_c-1) / ((1+e_o)(1+e_c)),     e_c = exp2(2*log2e*cn)
// REJECTED variants (do not retry):
//  - poly exp2 on VALU (r5): compiler scalarizes f32x2, trans HW is faster.
//    845us vs 560us.
//  - paired rcp rcp(Q0*Q1)+muls (r6/r7): 2 extra roundings compound through
//    the 64-step recurrence -> absmax 4.88e-4 -> 1.95e-3. Threshold is
//    2.197e-3 and edge_pass atomic-order noise needs that margin: r7 failed
//    the determinism tripwire with technically-passing absmax.
// NOTE: __launch_bounds__ 2nd arg MUST stay 4. (256,5) -> spills (r4:
// FETCH 64->160MB); (256,8) -> catastrophe (r1: 8.9GB scratch). Live set
// needs ~128 unified regs; occupancy is structurally 4 waves/SIMD.
__global__ __launch_bounds__(256, 4) void lstm_mfma(
    const float* __restrict__ x, const float* __restrict__ W_ih,
    const float* __restrict__ W_hh, const float* __restrict__ b_ih,
    const float* __restrict__ b_hh, const float* __restrict__ vcomb,
    float2* __restrict__ asx, float* __restrict__ a_dst,
    float2* __restrict__ da, int N)
{
  __shared__ __align__(16) _Float16 Hs0[32][64];
  __shared__ __align__(16) _Float16 Hs1[32][64];
  __shared__ __align__(16) _Float16 Xs0[32][8];
  __shared__ __align__(16) _Float16 Xs1[32][8];
  __shared__ __align__(16) _Float16 Zero8[8];
  __shared__ __align__(16) float    Hf[32][65];   // f32 final h (pad 65)

  const int tid   = threadIdx.x;
  const int lane  = tid & 63;
  const int wq    = tid >> 6;      // 0..3 gate-col slice
  const int col16 = lane & 15;
  const int grp   = lane >> 4;
  const int base  = blockIdx.x * 32;

  // ---- B fragments (fp16). g gate (n==2) scaled 2*LOG2E; i,f,o by LOG2E.
  f16x8 Bh[4][2], Bx[4];
  #pragma unroll
  for (int n=0;n<4;n++){
    const float sc = (n==2) ? 2.f*LOG2E : LOG2E;
    const int gate = n*64 + wq*16 + col16;
    #pragma unroll
    for (int kk=0;kk<2;kk++){
      const float* p = W_hh + gate*64 + kk*32 + grp*8;
      #pragma unroll
      for (int e=0;e<8;e++) Bh[n][kk][e] = (_Float16)(p[e]*sc);
    }
    f16x8 bx = {0,0,0,0,0,0,0,0};
    if (grp==0){
      #pragma unroll
      for (int e=0;e<5;e++) bx[e] = (_Float16)(W_ih[gate*5+e]*sc);
      bx[5] = (_Float16)((b_ih[gate]+b_hh[gate])*sc);
    }
    Bx[n] = bx;
  }

  // zero Hs0 (4 KB = 256 float4) + Zero8
  ((float4*)&Hs0[0][0])[tid] = float4{0.f,0.f,0.f,0.f};
  if (tid==0) ((float4*)Zero8)[0] = float4{0.f,0.f,0.f,0.f};

  // ---- distributed x staging: thread tid<160 owns (node=tid/5, elem=tid%5)
  const int  xn5  = tid/5, xe5 = tid - xn5*5;
  const bool xact = (tid < 160);
  const int  gxnode = base + xn5;
  const bool xlive  = xact && (gxnode < N);
  const float* xptr = x + (size_t)(xlive ? gxnode : 0)*(T_STEPS*F_INP) + xe5 + F_INP;
  if (xact){
    float v0 = xlive ? x[(size_t)gxnode*(T_STEPS*F_INP) + xe5] : 0.f;
    Xs0[xn5][xe5] = (_Float16)v0;
  }
  if (tid < 32){
    Xs0[tid][5]=(_Float16)1.f; Xs0[tid][6]=(_Float16)0.f; Xs0[tid][7]=(_Float16)0.f;
    Xs1[tid][5]=(_Float16)1.f; Xs1[tid][6]=(_Float16)0.f; Xs1[tid][7]=(_Float16)0.f;
  }

  // loop-invariant LDS element offsets
  const int sw = (col16&7)<<3;
  int roff0[2], roff1[2], xoffm[2], soff[2][4];
  const int j = wq*16 + col16;
  #pragma unroll
  for (int m=0;m<2;m++){
    const int nodeA = 16*m + col16;
    roff0[m] = nodeA*64 + ((grp*8) ^ sw);
    roff1[m] = nodeA*64 + ((32 + grp*8) ^ sw);
    xoffm[m] = nodeA*8;
    #pragma unroll
    for (int r=0;r<4;r++){
      const int node = 16*m + 4*grp + r;
      soff[m][r] = node*64 + (j ^ ((4*(grp&1)+r)<<3));
    }
  }

  float creg[2][4];
  #pragma unroll
  for (int m=0;m<2;m++)
    #pragma unroll
    for (int r=0;r<4;r++) creg[m][r]=0.f;

  __syncthreads();

#define LSTM_STEP(HC, HN, XC, XN, XOFF, LAST) {                                \
    float xval = 0.f;                                                          \
    if (!(LAST) && xlive) xval = xptr[XOFF];                                   \
    _Pragma("unroll")                                                          \
    for (int m=0;m<2;m++){                                                     \
      f16x8 a0 = *(const f16x8*)(&HC[0][0] + roff0[m]);                        \
      f16x8 a1 = *(const f16x8*)(&HC[0][0] + roff1[m]);                        \
      const _Float16* px = (grp==0) ? (&XC[0][0] + xoffm[m]) : Zero8;          \
      f16x8 ax = *(const f16x8*)px;                                            \
      f32x4 z4 = f32x4{0.f,0.f,0.f,0.f};                                       \
      f32x4 c0=z4, c1=z4, c2=z4, c3=z4;                                        \
      c0 = MF(a0, Bh[0][0], c0); c1 = MF(a0, Bh[1][0], c1);                    \
      c2 = MF(a0, Bh[2][0], c2); c3 = MF(a0, Bh[3][0], c3);                    \
      c0 = MF(a1, Bh[0][1], c0); c1 = MF(a1, Bh[1][1], c1);                    \
      c2 = MF(a1, Bh[2][1], c2); c3 = MF(a1, Bh[3][1], c3);                    \
      c0 = MF(ax, Bx[0],    c0); c1 = MF(ax, Bx[1],    c1);                    \
      c2 = MF(ax, Bx[2],    c2); c3 = MF(ax, Bx[3],    c3);                    \
      _Pragma("unroll")                                                        \
      for (int r=0;r<4;r++){                                                   \
        float e_i = exp2fast(-c0[r]);                                          \
        float e_f = exp2fast(-c1[r]);                                          \
        float zg2 = fminf(c2[r], 60.f);                                        \
        float e_g = exp2fast(zg2);                                             \
        float e_o = exp2fast(-c3[r]);                                          \
        float Ag = (1.f+e_i)*(1.f+e_g);                                        \
        float Bf = 1.f+e_f;                                                    \
        float rD = rcpf(Ag*Bf);                                                \
        float cn = (creg[m][r]*Ag + (e_g-1.f)*Bf)*rD;                          \
        creg[m][r] = cn;                                                       \
        float c2v = fminf(cn*(2.f*LOG2E), 120.f);                              \
        float e_c = exp2fast(c2v);                                             \
        float hv = (e_c-1.f)*rcpf((1.f+e_o)*(1.f+e_c));                        \
        if (LAST){                                                             \
          Hf[16*m+4*grp+r][j] = hv;                                            \
        } else {                                                               \
          (&HN[0][0])[soff[m][r]] = (_Float16)hv;                              \
        }                                                                      \
      }                                                                        \
    }                                                                          \
    if (!(LAST) && xact) XN[xn5][xe5] = (_Float16)xval;                        \
  }

  for (int tt=0; tt<T_STEPS/2; ++tt){
    LSTM_STEP(Hs0, Hs1, Xs0, Xs1, 0, false);
    __syncthreads();
    LSTM_STEP(Hs1, Hs0, Xs1, Xs0, F_INP, (tt==T_STEPS/2-1));
    __syncthreads();
    xptr += 2*F_INP;
  }
#undef LSTM_STEP

  // ---- fused GAT prep: 8 threads per node, dot h (f32, LDS) with vcomb.
  const int en = tid >> 3, es = tid & 7;
  const int gn2 = base + en;
  float as=0.f, ad=0.f, xf=0.f;
  #pragma unroll
  for (int q=0;q<8;q++){
    float hv = Hf[en][es*8+q];
    as = fmaf(hv, vcomb[es*8+q],     as);
    ad = fmaf(hv, vcomb[64+es*8+q],  ad);
    xf = fmaf(hv, vcomb[128+es*8+q], xf);
  }
  #pragma unroll
  for (int off=1; off<8; off<<=1){
    as += __shfl_xor(as, off);
    ad += __shfl_xor(ad, off);
    xf += __shfl_xor(xf, off);
  }
  if (es==0 && gn2 < N){
    asx[gn2]   = float2{as, xf};
    a_dst[gn2] = ad;
    da[gn2]    = float2{0.f, 0.f};   // {denom, oacc}
  }
}

// ---------------- GAT setup (one 64-thread block), wave-parallel:
// mode detect via ballot; vcomb = gat_w^T {att_src, att_dst, fc_w};
// bias-dot scalar via shfl reduce.
__global__ void gat_setup(const int* __restrict__ ei,
                          const float* __restrict__ gat_w,
                          const float* __restrict__ att_src,
                          const float* __restrict__ att_dst,
                          const float* __restrict__ fc_w,
                          const float* __restrict__ gat_bias,
                          const float* __restrict__ fc_b,
                          float* __restrict__ vcomb,
                          unsigned* __restrict__ mode)
{
  int j = threadIdx.x;   // 0..63, one full wave
  unsigned long long nz = __ballot(ei[2*j+1] != 0);
  float bdp = gat_bias[j]*fc_w[j];
  #pragma unroll
  for (int off=32; off; off>>=1) bdp += __shfl_down(bdp, off);
  if (j==0){
    *mode = (nz==0ULL) ? 1u : 0u;
    vcomb[192] = bdp + fc_b[0];
  }
  float va=0.f, vd=0.f, vf=0.f;
  #pragma unroll 8
  for (int k=0;k<64;k++){
    float g = gat_w[k*64+j];
    va += att_src[k]*g;
    vd += att_dst[k]*g;
    vf += fc_w[k]*g;
  }
  vcomb[j]=va; vcomb[64+j]=vd; vcomb[128+j]=vf;
}

__device__ __forceinline__ void load_edge(const int* ei, unsigned mode,
                                          long long e, long long E,
                                          int& s, int& d)
{
  if (e>=E){ s=d=(int)(e-E); }
  else if (mode){
    const long long* e64 = (const long long*)ei;
    s=(int)e64[e]; d=(int)e64[E+e];
  } else {
    s=ei[e]; d=ei[E+e];
  }
}

// single pass: softmax normalization deferred to finalize.
// out[d] = (sum ew*xf_s)/(sum ew). asx packs {a_src, xfv} -> one 8B gather.
// da interleaves {denom, oacc} -> both atomics hit one cacheline.
__global__ __launch_bounds__(256) void edge_pass(
    const int* __restrict__ ei, const unsigned* __restrict__ mode_p,
    const float2* __restrict__ asx, const float* __restrict__ a_dst,
    float2* __restrict__ da,
    long long E, long long total)
{
  long long e = (long long)blockIdx.x*256 + threadIdx.x;
  if (e>=total) return;
  int s,d;
  load_edge(ei, *mode_p, e, E, s, d);
  float2 sv = asx[s];
  float al = leaky(sv.x + a_dst[d], 0.2f);
  float ew = __expf(al);
  atomicAdd(&da[d].x, ew);
  atomicAdd(&da[d].y, ew * sv.y);
}

__global__ __launch_bounds__(256) void finalize(
    const float2* __restrict__ da, const float* __restrict__ vcomb,
    float* __restrict__ out, int N)
{
  int n = blockIdx.x*256+threadIdx.x;
  if (n>=N) return;
  float2 v = da[n];
  out[n] = leaky(v.y * rcpf(v.x) + vcomb[192], 0.01f);
}

extern "C" void kernel_launch(void* const* d_in, const int* in_sizes, int n_in,
                              void* d_out, int out_size, void* d_ws, size_t ws_size,
                              hipStream_t stream)
{
  const float* x      = (const float*)d_in[0];
  const float* W_ih   = (const float*)d_in[1];
  const float* W_hh   = (const float*)d_in[2];
  const float* b_ih   = (const float*)d_in[3];
  const float* b_hh   = (const float*)d_in[4];
  const float* gat_w  = (const float*)d_in[5];
  const float* att_s  = (const float*)d_in[6];
  const float* att_d  = (const float*)d_in[7];
  const float* gat_b  = (const float*)d_in[8];
  const float* fc_w   = (const float*)d_in[9];
  const float* fc_b   = (const float*)d_in[10];
  const int*   ei     = (const int*)d_in[11];

  const int N = in_sizes[0]/(T_STEPS*F_INP);
  const long long E = in_sizes[11]/2;
  const long long total = E + N;

  float* ws = (float*)d_ws;
  size_t off = 0;
  float2* asx    = (float2*)(ws + off); off += (size_t)2*N;
  float* a_dst   = ws + off; off += (size_t)N;
  float2* da     = (float2*)(ws + off); off += (size_t)2*N;
  float* vcomb   = ws + off; off += 256;
  unsigned* mode = (unsigned*)(ws + off); off += 1;

  gat_setup<<<1,64,0,stream>>>(ei, gat_w, att_s, att_d, fc_w, gat_b, fc_b, vcomb, mode);

  lstm_mfma<<<dim3((N+31)/32), dim3(256), 0, stream>>>(
      x, W_ih, W_hh, b_ih, b_hh, vcomb, asx, a_dst, da, N);

  int eb = (int)((total+255)/256);
  edge_pass<<<dim3(eb), dim3(256), 0, stream>>>(ei, mode, asx, a_dst, da, E, total);

  finalize<<<dim3((N+255)/256), dim3(256), 0, stream>>>(da, vcomb, (float*)d_out, N);
}

// Round 9
// 646.609 us; speedup vs baseline: 1.3361x; 1.0035x over previous
//
#include <hip/hip_runtime.h>
#include <cstdint>
#include <cstddef>

#define T_STEPS 64
#define F_INP 5
#define LOG2E 1.44269504088896340736f

typedef _Float16 f16x8 __attribute__((ext_vector_type(8)));
typedef float f32x4 __attribute__((ext_vector_type(4)));

__device__ __forceinline__ float leaky(float x, float s){ return x>0.f? x : s*x; }
__device__ __forceinline__ float rcpf(float x){ return __builtin_amdgcn_rcpf(x); }
__device__ __forceinline__ float exp2fast(float x){ return __builtin_amdgcn_exp2f(x); }

#define MF(a,b,c) __builtin_amdgcn_mfma_f32_16x16x32_f16((a),(b),(c),0,0,0)

// ---------------- MFMA LSTM + fused GAT-prep epilogue.
// 32 nodes/block, 4 waves lockstep. Wave wq owns gate-cols [16wq,16wq+16).
// Activation: r3-PROVEN form. 5 exp + 2 DIRECT rcp per cell element.
//   cn = (c*Ag + (e_g-1)*Bf) / (Ag*Bf),  Ag=(1+e_i)(1+e_g), Bf=1+e_f
//   hv = (e_c-1) / ((1+e_o)(1+e_c)),     e_c = exp2(2*log2e*cn)
// Port accounting (r8 counters): 56 trans x 16cy = 53.6% of wall + 180 VALU
// x 2cy = 21.5% -> 75.1% = measured VALUBusy. Floor at port saturation is
// ~420us; needs >4 waves/SIMD -> walled by the 128-unified-reg live set.
// REJECTED (do not retry):
//  - poly exp2 on VALU (r5): compiler scalarizes f32x2; 845us vs 560us.
//  - paired rcp rcp(Q0*Q1)+muls (r6/r7): extra roundings compound through
//    the 64-step recurrence -> absmax 4.88e-4 -> 1.95e-3; eats the margin
//    the edge_pass atomic-order noise needs (r7 tripwire fail).
//  - __launch_bounds__ !=4: (256,5) spills (r4: FETCH 64->160MB);
//    (256,8) catastrophe (r1: 8.9GB scratch).
// r9: self-loop edge folded here: da init = {ew_self, ew_self*xf} so
// edge_pass handles only the E real edges (no e>=E branch, -5.9% items).
__global__ __launch_bounds__(256, 4) void lstm_mfma(
    const float* __restrict__ x, const float* __restrict__ W_ih,
    const float* __restrict__ W_hh, const float* __restrict__ b_ih,
    const float* __restrict__ b_hh, const float* __restrict__ vcomb,
    float2* __restrict__ asx, float* __restrict__ a_dst,
    float2* __restrict__ da, int N)
{
  __shared__ __align__(16) _Float16 Hs0[32][64];
  __shared__ __align__(16) _Float16 Hs1[32][64];
  __shared__ __align__(16) _Float16 Xs0[32][8];
  __shared__ __align__(16) _Float16 Xs1[32][8];
  __shared__ __align__(16) _Float16 Zero8[8];
  __shared__ __align__(16) float    Hf[32][65];   // f32 final h (pad 65)

  const int tid   = threadIdx.x;
  const int lane  = tid & 63;
  const int wq    = tid >> 6;      // 0..3 gate-col slice
  const int col16 = lane & 15;
  const int grp   = lane >> 4;
  const int base  = blockIdx.x * 32;

  // ---- B fragments (fp16). g gate (n==2) scaled 2*LOG2E; i,f,o by LOG2E.
  f16x8 Bh[4][2], Bx[4];
  #pragma unroll
  for (int n=0;n<4;n++){
    const float sc = (n==2) ? 2.f*LOG2E : LOG2E;
    const int gate = n*64 + wq*16 + col16;
    #pragma unroll
    for (int kk=0;kk<2;kk++){
      const float* p = W_hh + gate*64 + kk*32 + grp*8;
      #pragma unroll
      for (int e=0;e<8;e++) Bh[n][kk][e] = (_Float16)(p[e]*sc);
    }
    f16x8 bx = {0,0,0,0,0,0,0,0};
    if (grp==0){
      #pragma unroll
      for (int e=0;e<5;e++) bx[e] = (_Float16)(W_ih[gate*5+e]*sc);
      bx[5] = (_Float16)((b_ih[gate]+b_hh[gate])*sc);
    }
    Bx[n] = bx;
  }

  // zero Hs0 (4 KB = 256 float4) + Zero8
  ((float4*)&Hs0[0][0])[tid] = float4{0.f,0.f,0.f,0.f};
  if (tid==0) ((float4*)Zero8)[0] = float4{0.f,0.f,0.f,0.f};

  // ---- distributed x staging: thread tid<160 owns (node=tid/5, elem=tid%5)
  const int  xn5  = tid/5, xe5 = tid - xn5*5;
  const bool xact = (tid < 160);
  const int  gxnode = base + xn5;
  const bool xlive  = xact && (gxnode < N);
  const float* xptr = x + (size_t)(xlive ? gxnode : 0)*(T_STEPS*F_INP) + xe5 + F_INP;
  if (xact){
    float v0 = xlive ? x[(size_t)gxnode*(T_STEPS*F_INP) + xe5] : 0.f;
    Xs0[xn5][xe5] = (_Float16)v0;
  }
  if (tid < 32){
    Xs0[tid][5]=(_Float16)1.f; Xs0[tid][6]=(_Float16)0.f; Xs0[tid][7]=(_Float16)0.f;
    Xs1[tid][5]=(_Float16)1.f; Xs1[tid][6]=(_Float16)0.f; Xs1[tid][7]=(_Float16)0.f;
  }

  // loop-invariant LDS element offsets
  const int sw = (col16&7)<<3;
  int roff0[2], roff1[2], xoffm[2], soff[2][4];
  const int j = wq*16 + col16;
  #pragma unroll
  for (int m=0;m<2;m++){
    const int nodeA = 16*m + col16;
    roff0[m] = nodeA*64 + ((grp*8) ^ sw);
    roff1[m] = nodeA*64 + ((32 + grp*8) ^ sw);
    xoffm[m] = nodeA*8;
    #pragma unroll
    for (int r=0;r<4;r++){
      const int node = 16*m + 4*grp + r;
      soff[m][r] = node*64 + (j ^ ((4*(grp&1)+r)<<3));
    }
  }

  float creg[2][4];
  #pragma unroll
  for (int m=0;m<2;m++)
    #pragma unroll
    for (int r=0;r<4;r++) creg[m][r]=0.f;

  __syncthreads();

#define LSTM_STEP(HC, HN, XC, XN, XOFF, LAST) {                                \
    float xval = 0.f;                                                          \
    if (!(LAST) && xlive) xval = xptr[XOFF];                                   \
    _Pragma("unroll")                                                          \
    for (int m=0;m<2;m++){                                                     \
      f16x8 a0 = *(const f16x8*)(&HC[0][0] + roff0[m]);                        \
      f16x8 a1 = *(const f16x8*)(&HC[0][0] + roff1[m]);                        \
      const _Float16* px = (grp==0) ? (&XC[0][0] + xoffm[m]) : Zero8;          \
      f16x8 ax = *(const f16x8*)px;                                            \
      f32x4 z4 = f32x4{0.f,0.f,0.f,0.f};                                       \
      f32x4 c0=z4, c1=z4, c2=z4, c3=z4;                                        \
      c0 = MF(a0, Bh[0][0], c0); c1 = MF(a0, Bh[1][0], c1);                    \
      c2 = MF(a0, Bh[2][0], c2); c3 = MF(a0, Bh[3][0], c3);                    \
      c0 = MF(a1, Bh[0][1], c0); c1 = MF(a1, Bh[1][1], c1);                    \
      c2 = MF(a1, Bh[2][1], c2); c3 = MF(a1, Bh[3][1], c3);                    \
      c0 = MF(ax, Bx[0],    c0); c1 = MF(ax, Bx[1],    c1);                    \
      c2 = MF(ax, Bx[2],    c2); c3 = MF(ax, Bx[3],    c3);                    \
      _Pragma("unroll")                                                        \
      for (int r=0;r<4;r++){                                                   \
        float e_i = exp2fast(-c0[r]);                                          \
        float e_f = exp2fast(-c1[r]);                                          \
        float zg2 = fminf(c2[r], 60.f);                                        \
        float e_g = exp2fast(zg2);                                             \
        float e_o = exp2fast(-c3[r]);                                          \
        float Ag = (1.f+e_i)*(1.f+e_g);                                        \
        float Bf = 1.f+e_f;                                                    \
        float rD = rcpf(Ag*Bf);                                                \
        float cn = (creg[m][r]*Ag + (e_g-1.f)*Bf)*rD;                          \
        creg[m][r] = cn;                                                       \
        float c2v = fminf(cn*(2.f*LOG2E), 120.f);                              \
        float e_c = exp2fast(c2v);                                             \
        float hv = (e_c-1.f)*rcpf((1.f+e_o)*(1.f+e_c));                        \
        if (LAST){                                                             \
          Hf[16*m+4*grp+r][j] = hv;                                            \
        } else {                                                               \
          (&HN[0][0])[soff[m][r]] = (_Float16)hv;                              \
        }                                                                      \
      }                                                                        \
    }                                                                          \
    if (!(LAST) && xact) XN[xn5][xe5] = (_Float16)xval;                        \
  }

  for (int tt=0; tt<T_STEPS/2; ++tt){
    LSTM_STEP(Hs0, Hs1, Xs0, Xs1, 0, false);
    __syncthreads();
    LSTM_STEP(Hs1, Hs0, Xs1, Xs0, F_INP, (tt==T_STEPS/2-1));
    __syncthreads();
    xptr += 2*F_INP;
  }
#undef LSTM_STEP

  // ---- fused GAT prep: 8 threads per node, dot h (f32, LDS) with vcomb.
  const int en = tid >> 3, es = tid & 7;
  const int gn2 = base + en;
  float as=0.f, ad=0.f, xf=0.f;
  #pragma unroll
  for (int q=0;q<8;q++){
    float hv = Hf[en][es*8+q];
    as = fmaf(hv, vcomb[es*8+q],     as);
    ad = fmaf(hv, vcomb[64+es*8+q],  ad);
    xf = fmaf(hv, vcomb[128+es*8+q], xf);
  }
  #pragma unroll
  for (int off=1; off<8; off<<=1){
    as += __shfl_xor(as, off);
    ad += __shfl_xor(ad, off);
    xf += __shfl_xor(xf, off);
  }
  if (es==0 && gn2 < N){
    asx[gn2]   = float2{as, xf};
    a_dst[gn2] = ad;
    // self-loop edge folded here (was edge_pass's e>=E branch):
    float ew = __expf(leaky(as + ad, 0.2f));
    da[gn2]   = float2{ew, ew*xf};   // {denom, oacc} init
  }
}

// ---------------- GAT setup (one 64-thread block), wave-parallel:
// mode detect via ballot; vcomb = gat_w^T {att_src, att_dst, fc_w};
// bias-dot scalar via shfl reduce.
__global__ void gat_setup(const int* __restrict__ ei,
                          const float* __restrict__ gat_w,
                          const float* __restrict__ att_src,
                          const float* __restrict__ att_dst,
                          const float* __restrict__ fc_w,
                          const float* __restrict__ gat_bias,
                          const float* __restrict__ fc_b,
                          float* __restrict__ vcomb,
                          unsigned* __restrict__ mode)
{
  int j = threadIdx.x;   // 0..63, one full wave
  unsigned long long nz = __ballot(ei[2*j+1] != 0);
  float bdp = gat_bias[j]*fc_w[j];
  #pragma unroll
  for (int off=32; off; off>>=1) bdp += __shfl_down(bdp, off);
  if (j==0){
    *mode = (nz==0ULL) ? 1u : 0u;
    vcomb[192] = bdp + fc_b[0];
  }
  float va=0.f, vd=0.f, vf=0.f;
  #pragma unroll 8
  for (int k=0;k<64;k++){
    float g = gat_w[k*64+j];
    va += att_src[k]*g;
    vd += att_dst[k]*g;
    vf += fc_w[k]*g;
  }
  vcomb[j]=va; vcomb[64+j]=vd; vcomb[128+j]=vf;
}

// single pass over the E real edges (self-loops pre-folded into da by the
// lstm epilogue). out[d] = (sum ew*xf_s)/(sum ew), normalization deferred
// to finalize. asx packs {a_src, xfv} -> one 8B gather; da interleaves
// {denom, oacc} -> both atomics hit one cacheline.
__global__ __launch_bounds__(256) void edge_pass(
    const int* __restrict__ ei, const unsigned* __restrict__ mode_p,
    const float2* __restrict__ asx, const float* __restrict__ a_dst,
    float2* __restrict__ da, long long E)
{
  long long e = (long long)blockIdx.x*256 + threadIdx.x;
  if (e>=E) return;
  int s,d;
  if (*mode_p){
    const long long* e64 = (const long long*)ei;
    s=(int)e64[e]; d=(int)e64[E+e];
  } else {
    s=ei[e]; d=ei[E+e];
  }
  float2 sv = asx[s];
  float al = leaky(sv.x + a_dst[d], 0.2f);
  float ew = __expf(al);
  atomicAdd(&da[d].x, ew);
  atomicAdd(&da[d].y, ew * sv.y);
}

__global__ __launch_bounds__(256) void finalize(
    const float2* __restrict__ da, const float* __restrict__ vcomb,
    float* __restrict__ out, int N)
{
  int n = blockIdx.x*256+threadIdx.x;
  if (n>=N) return;
  float2 v = da[n];
  out[n] = leaky(v.y * rcpf(v.x) + vcomb[192], 0.01f);
}

extern "C" void kernel_launch(void* const* d_in, const int* in_sizes, int n_in,
                              void* d_out, int out_size, void* d_ws, size_t ws_size,
                              hipStream_t stream)
{
  const float* x      = (const float*)d_in[0];
  const float* W_ih   = (const float*)d_in[1];
  const float* W_hh   = (const float*)d_in[2];
  const float* b_ih   = (const float*)d_in[3];
  const float* b_hh   = (const float*)d_in[4];
  const float* gat_w  = (const float*)d_in[5];
  const float* att_s  = (const float*)d_in[6];
  const float* att_d  = (const float*)d_in[7];
  const float* gat_b  = (const float*)d_in[8];
  const float* fc_w   = (const float*)d_in[9];
  const float* fc_b   = (const float*)d_in[10];
  const int*   ei     = (const int*)d_in[11];

  const int N = in_sizes[0]/(T_STEPS*F_INP);
  const long long E = in_sizes[11]/2;

  float* ws = (float*)d_ws;
  size_t off = 0;
  float2* asx    = (float2*)(ws + off); off += (size_t)2*N;
  float* a_dst   = ws + off; off += (size_t)N;
  float2* da     = (float2*)(ws + off); off += (size_t)2*N;
  float* vcomb   = ws + off; off += 256;
  unsigned* mode = (unsigned*)(ws + off); off += 1;

  gat_setup<<<1,64,0,stream>>>(ei, gat_w, att_s, att_d, fc_w, gat_b, fc_b, vcomb, mode);

  lstm_mfma<<<dim3((N+31)/32), dim3(256), 0, stream>>>(
      x, W_ih, W_hh, b_ih, b_hh, vcomb, asx, a_dst, da, N);

  int eb = (int)((E+255)/256);
  edge_pass<<<dim3(eb), dim3(256), 0, stream>>>(ei, mode, asx, a_dst, da, E);

  finalize<<<dim3((N+255)/256), dim3(256), 0, stream>>>(da, vcomb, (float*)d_out, N);
}